// Round 4
// baseline (244.473 us; speedup 1.0000x reference)
//
#include <hip/hip_runtime.h>

// SparseGlobalBroadcast: out[n][c] = in_feat[n][c] + glob_feat[batch_idx[n]][c]
// N = 1e6, C = 128, B = 8, fp32. Memory-bound streaming gather-add.
// R3: A/B isolation — keep the x4 strided unroll from R2, REMOVE all
//     nontemporal hints (suspected culprit for the 209->240us regression).

#define SGB_C   128
#define SGB_C4  (SGB_C / 4)   // 32 f32x4 per row -> row = idx >> 5

typedef float f32x4 __attribute__((ext_vector_type(4)));

__global__ __launch_bounds__(256) void SparseGlobalBroadcast_27762668601803_kernel(
    const f32x4* __restrict__ in4,
    const f32x4* __restrict__ glob4,    // B * C4 vectors (256 total)
    const int*   __restrict__ bidx,
    f32x4*       __restrict__ out4,
    int n4,                             // N * C/4 total f32x4 elements
    int b_times_c4)                     // B * C4 (256)
{
    __shared__ f32x4 g_lds[8 * SGB_C4];   // 4 KB (B=8)

    const int t = threadIdx.x;
    if (t < b_times_c4) g_lds[t] = glob4[t];
    __syncthreads();

    const int stride  = gridDim.x * blockDim.x;
    const int stride4 = stride * 4;
    int i = blockIdx.x * blockDim.x + t;

    // Main loop: 4 independent strided f32x4 elements per iteration.
    for (; i + 3 * stride < n4; i += stride4) {
        const int i0 = i;
        const int i1 = i + stride;
        const int i2 = i + 2 * stride;
        const int i3 = i + 3 * stride;

        // Issue all 4 streamed loads first (4-deep MLP).
        f32x4 a0 = in4[i0];
        f32x4 a1 = in4[i1];
        f32x4 a2 = in4[i2];
        f32x4 a3 = in4[i3];

        const int b0 = bidx[i0 >> 5];
        const int b1 = bidx[i1 >> 5];
        const int b2 = bidx[i2 >> 5];
        const int b3 = bidx[i3 >> 5];

        a0 += g_lds[b0 * SGB_C4 + (i0 & (SGB_C4 - 1))];
        a1 += g_lds[b1 * SGB_C4 + (i1 & (SGB_C4 - 1))];
        a2 += g_lds[b2 * SGB_C4 + (i2 & (SGB_C4 - 1))];
        a3 += g_lds[b3 * SGB_C4 + (i3 & (SGB_C4 - 1))];

        out4[i0] = a0;
        out4[i1] = a1;
        out4[i2] = a2;
        out4[i3] = a3;
    }

    // Tail: remaining strided singles.
    for (; i < n4; i += stride) {
        const int b = bidx[i >> 5];
        f32x4 a = in4[i];
        a += g_lds[b * SGB_C4 + (i & (SGB_C4 - 1))];
        out4[i] = a;
    }
}

extern "C" void kernel_launch(void* const* d_in, const int* in_sizes, int n_in,
                              void* d_out, int out_size, void* d_ws, size_t ws_size,
                              hipStream_t stream) {
    const f32x4* in4   = (const f32x4*)d_in[0];   // in_feat  [N, C] fp32
    const f32x4* glob4 = (const f32x4*)d_in[1];   // glob_feat [B, C] fp32
    const int*   bidx  = (const int*)d_in[2];     // batch_idx [N] int32
    f32x4*       out4  = (f32x4*)d_out;

    const int N  = in_sizes[2];                 // 1,000,000
    const int n4 = N * SGB_C4;                  // 32,000,000 f32x4 elements
    const int b_times_c4 = in_sizes[1] / 4;     // B * C4 = 256

    const int block = 256;
    int grid = (n4 + block - 1) / block;
    if (grid > 2048) grid = 2048;               // grid-stride the rest

    SparseGlobalBroadcast_27762668601803_kernel<<<grid, block, 0, stream>>>(
        in4, glob4, bidx, out4, n4, b_times_c4);
}

// Round 5
// 188.070 us; speedup vs baseline: 1.2999x; 1.2999x over previous
//
#include <hip/hip_runtime.h>

// SparseGlobalBroadcast: out[n][c] = in_feat[n][c] + glob_feat[batch_idx[n]][c]
// N = 1e6, C = 128, B = 8, fp32. Memory-bound streaming gather-add.
// R4: block-chunked x4 unroll — each block owns a CONTIGUOUS 16 KB region
//     (4 chunks of 256 f32x4); thread t handles {0,256,512,768}+t. Keeps
//     per-instruction coalescing AND tight address locality (R3's 8MB-apart
//     strided unroll regressed). One-shot grid (31250 blocks), no loop.

#define SGB_C    128
#define SGB_C4   (SGB_C / 4)     // 32 f32x4 per row -> row = idx >> 5
#define CHUNK    256             // f32x4 per chunk (= blockDim)
#define PERBLK   (4 * CHUNK)     // f32x4 per block (16 KB)

typedef float f32x4 __attribute__((ext_vector_type(4)));

__global__ __launch_bounds__(256) void SparseGlobalBroadcast_27762668601803_kernel(
    const f32x4* __restrict__ in4,
    const f32x4* __restrict__ glob4,    // B * C4 vectors (256 total)
    const int*   __restrict__ bidx,
    f32x4*       __restrict__ out4,
    int n4,                             // N * C/4 total f32x4 elements
    int b_times_c4)                     // B * C4 (256)
{
    __shared__ f32x4 g_lds[8 * SGB_C4];   // 4 KB (B=8)

    const int t = threadIdx.x;
    if (t < b_times_c4) g_lds[t] = glob4[t];
    __syncthreads();

    const int base = blockIdx.x * PERBLK + t;
    const int i0 = base;
    const int i1 = base + CHUNK;
    const int i2 = base + 2 * CHUNK;
    const int i3 = base + 3 * CHUNK;

    if (i3 < n4) {
        // Fast path: whole 16 KB block region in bounds.
        f32x4 a0 = in4[i0];
        f32x4 a1 = in4[i1];
        f32x4 a2 = in4[i2];
        f32x4 a3 = in4[i3];

        const int b0 = bidx[i0 >> 5];
        const int b1 = bidx[i1 >> 5];
        const int b2 = bidx[i2 >> 5];
        const int b3 = bidx[i3 >> 5];

        a0 += g_lds[b0 * SGB_C4 + (i0 & (SGB_C4 - 1))];
        a1 += g_lds[b1 * SGB_C4 + (i1 & (SGB_C4 - 1))];
        a2 += g_lds[b2 * SGB_C4 + (i2 & (SGB_C4 - 1))];
        a3 += g_lds[b3 * SGB_C4 + (i3 & (SGB_C4 - 1))];

        out4[i0] = a0;
        out4[i1] = a1;
        out4[i2] = a2;
        out4[i3] = a3;
    } else {
        // Tail block: per-element guards.
        #pragma unroll
        for (int k = 0; k < 4; ++k) {
            const int i = base + k * CHUNK;
            if (i < n4) {
                f32x4 a = in4[i];
                a += g_lds[bidx[i >> 5] * SGB_C4 + (i & (SGB_C4 - 1))];
                out4[i] = a;
            }
        }
    }
}

extern "C" void kernel_launch(void* const* d_in, const int* in_sizes, int n_in,
                              void* d_out, int out_size, void* d_ws, size_t ws_size,
                              hipStream_t stream) {
    const f32x4* in4   = (const f32x4*)d_in[0];   // in_feat  [N, C] fp32
    const f32x4* glob4 = (const f32x4*)d_in[1];   // glob_feat [B, C] fp32
    const int*   bidx  = (const int*)d_in[2];     // batch_idx [N] int32
    f32x4*       out4  = (f32x4*)d_out;

    const int N  = in_sizes[2];                 // 1,000,000
    const int n4 = N * SGB_C4;                  // 32,000,000 f32x4 elements
    const int b_times_c4 = in_sizes[1] / 4;     // B * C4 = 256

    const int block = 256;
    const int grid  = (n4 + PERBLK - 1) / PERBLK;   // 31250 one-shot blocks

    SparseGlobalBroadcast_27762668601803_kernel<<<grid, block, 0, stream>>>(
        in4, glob4, bidx, out4, n4, b_times_c4);
}